// Round 8
// baseline (272.501 us; speedup 1.0000x reference)
//
#include <hip/hip_runtime.h>

#define B_SZ    2
#define S_LEN   2048
#define D_MODEL 1024
#define H_NUM   16
#define DK_H    64
#define M_ROWS  (B_SZ * S_LEN)   // 4096

typedef __attribute__((ext_vector_type(8))) short  short8;
typedef __attribute__((ext_vector_type(4))) short  short4v;
typedef __attribute__((ext_vector_type(4))) float  floatx4;

// fp32 -> bf16 round-to-nearest-even (finite inputs only)
__device__ __forceinline__ short f2b(float f) {
    union { float f; unsigned u; } x; x.f = f;
    unsigned u = x.u + 0x7fffu + ((x.u >> 16) & 1u);
    return (short)(u >> 16);
}
// truncating fp32 -> bf16 (for P in [0, 2^-5]: bias cancels in O/l ratio)
__device__ __forceinline__ short f2b_t(float f) {
    union { float f; unsigned u; } x; x.f = f;
    return (short)(x.u >> 16);
}

typedef __attribute__((address_space(1))) const unsigned int gu32;
typedef __attribute__((address_space(3))) unsigned int       lu32;
__device__ __forceinline__ void gload_lds16(const short* g, short* l) {
    __builtin_amdgcn_global_load_lds((gu32*)g, (lu32*)l, 16, 0, 0);
}

// log2(e)/sqrt(DK): folded into Q so softmax runs in exp2 domain
#define QSCALE 0.18033688011112042f
// fixed softmax shift (exp2-domain scores ~N(0,1.44); 12 >> any row max)
#define SM_SHIFT 12.0f

// ---------------------------------------------------------------------------
// fp32 -> bf16 convert, all 7 tensors in one launch.
// grid (1024, 7), 256 thr. y<3: x-tensors (4 passes); y>=3: weights (1 pass).
// ---------------------------------------------------------------------------
__global__ void cvt_all_kernel(const float* __restrict__ xq, const float* __restrict__ xk,
                               const float* __restrict__ xv, const float* __restrict__ wq,
                               const float* __restrict__ wk, const float* __restrict__ wv,
                               const float* __restrict__ wo,
                               short* __restrict__ oxq, short* __restrict__ oxk,
                               short* __restrict__ oxv, short* __restrict__ owq,
                               short* __restrict__ owk, short* __restrict__ owv,
                               short* __restrict__ owo)
{
    const int y = blockIdx.y;
    const float* in;
    short* out;
    switch (y) {
        case 0: in = xq; out = oxq; break;
        case 1: in = xk; out = oxk; break;
        case 2: in = xv; out = oxv; break;
        case 3: in = wq; out = owq; break;
        case 4: in = wk; out = owk; break;
        case 5: in = wv; out = owv; break;
        default: in = (y == 6) ? wo : wv; out = (y == 6) ? owo : owv; break;
    }
    const int npass = (y < 3) ? 4 : 1;
    int base = blockIdx.x * 1024 + threadIdx.x * 4;
    for (int p = 0; p < npass; ++p) {
        int i = base + p * 1048576;
        float4 v = *(const float4*)(in + i);
        short4v r;
        r[0] = f2b(v.x); r[1] = f2b(v.y); r[2] = f2b(v.z); r[3] = f2b(v.w);
        *(short4v*)(out + i) = r;
    }
}

// ---------------------------------------------------------------------------
// Fused QKV projection (m97 structure). Q scaled by log2e/8. Q,K out
// [B,H,S,DK]; V out transposed [B,H,DK,S].
// ---------------------------------------------------------------------------
__global__ __launch_bounds__(256)
void gemm_qkv_kernel(const short* __restrict__ xq, const short* __restrict__ xk,
                     const short* __restrict__ xv,
                     const short* __restrict__ wq, const short* __restrict__ wk,
                     const short* __restrict__ wv,
                     const float* __restrict__ bq, const float* __restrict__ bk,
                     const float* __restrict__ bv,
                     short* __restrict__ Qp, short* __restrict__ Kp, short* __restrict__ Vt)
{
    __shared__ short sa[128 * 32];
    __shared__ short sb[128 * 32];

    const int which = blockIdx.y >> 3;
    const short* A    = (which == 0) ? xq : (which == 1) ? xk : xv;
    const short* W    = (which == 0) ? wq : (which == 1) ? wk : wv;
    const float* bias = (which == 0) ? bq : (which == 1) ? bk : bv;
    const float scale = (which == 0) ? QSCALE : 1.0f;

    const int nb = (blockIdx.y & 7) * 128;
    const int m0 = blockIdx.x * 128;
    const int t = threadIdx.x, wave = t >> 6, lane = t & 63;
    const int quad = lane >> 4, l16 = lane & 15;
    const int wm = (wave & 1) * 64, wn = (wave >> 1) * 64;

    const int r0 = t >> 2, cs = t & 3;
    const int c0 = cs ^ ((r0 >> 1) & 3);
    const short* Ab0 = A + (size_t)(m0 + r0) * D_MODEL + c0 * 8;
    const short* Ab1 = Ab0 + (size_t)64 * D_MODEL;
    const short* Bb0 = W + (size_t)(nb + r0) * D_MODEL + c0 * 8;
    const short* Bb1 = Bb0 + (size_t)64 * D_MODEL;
    short* sa0 = sa + t * 8;  short* sa1 = sa + 2048 + t * 8;
    short* sb0 = sb + t * 8;  short* sb1 = sb + 2048 + t * 8;

    int a_off[4], b_off[4];
#pragma unroll
    for (int i = 0; i < 4; ++i) {
        int ar = wm + i * 16 + l16;
        a_off[i] = ar * 32 + ((quad ^ ((ar >> 1) & 3)) * 8);
        int br = wn + i * 16 + l16;
        b_off[i] = br * 32 + ((quad ^ ((br >> 1) & 3)) * 8);
    }

    floatx4 acc[4][4] = {};
    for (int k0 = 0; k0 < D_MODEL; k0 += 32) {
        __syncthreads();
        gload_lds16(Ab0 + k0, sa0);
        gload_lds16(Ab1 + k0, sa1);
        gload_lds16(Bb0 + k0, sb0);
        gload_lds16(Bb1 + k0, sb1);
        __syncthreads();
        short8 af[4], bf[4];
#pragma unroll
        for (int i = 0; i < 4; ++i) af[i] = *(const short8*)(sa + a_off[i]);
#pragma unroll
        for (int i = 0; i < 4; ++i) bf[i] = *(const short8*)(sb + b_off[i]);
#pragma unroll
        for (int mt = 0; mt < 4; ++mt)
#pragma unroll
            for (int nt = 0; nt < 4; ++nt)
                acc[mt][nt] = __builtin_amdgcn_mfma_f32_16x16x32_bf16(af[mt], bf[nt], acc[mt][nt], 0, 0, 0);
    }

#pragma unroll
    for (int nt = 0; nt < 4; ++nt) {
        int ncol = nb + wn + nt * 16 + l16;
        int h = ncol >> 6, dk = ncol & 63;
        float bv_ = bias[ncol];
#pragma unroll
        for (int mt = 0; mt < 4; ++mt) {
            int mrow0 = m0 + wm + mt * 16 + quad * 4;
            int bb = mrow0 >> 11, s0 = mrow0 & (S_LEN - 1);
            if (which < 2) {
                short* Out = (which == 0) ? Qp : Kp;
#pragma unroll
                for (int r = 0; r < 4; ++r) {
                    float v = (acc[mt][nt][r] + bv_) * scale;
                    Out[(((size_t)bb * H_NUM + h) * S_LEN + (s0 + r)) * DK_H + dk] = f2b(v);
                }
            } else {
                short4v pk;
#pragma unroll
                for (int r = 0; r < 4; ++r) pk[r] = f2b(acc[mt][nt][r] + bv_);
                *(short4v*)(&Vt[(((size_t)bb * H_NUM + h) * DK_H + dk) * S_LEN + s0]) = pk;
            }
        }
    }
}

// ---------------------------------------------------------------------------
// Balanced flash attention, XCD-local KV. Linear block id c = x + 8y is
// re-derived as bh = c&31, pairtile = c>>5 -> all 8 blocks of one bh land on
// XCD bh%8 (4 bh x 768KB = 3MB Q/K/V per XCD L2 -> no HBM re-fetch).
// Block = 8 waves: waves 0-3 tile p, waves 4-7 tile 15-p (per-SIMD work
// uniform chip-wide). Wave = 32 q-rows. K AND V double-buffered in registers
// with static selection (manual x2 unroll). Fixed-shift exp2 softmax;
// row-sum via ones-column MFMA. No barriers.
// ---------------------------------------------------------------------------
__global__ __launch_bounds__(512, 2)
void attn_kernel(const short* __restrict__ Qp, const short* __restrict__ Kp,
                 const short* __restrict__ Vt, short* __restrict__ Xa)
{
    __shared__ short pl[8][16 * 72];   // per-wave P round-trip

    const int c = (int)(blockIdx.x + 8 * blockIdx.y);
    const int bh = c & 31;                       // XCD = bh % 8
    const int pairtile = c >> 5;                 // [0,8)
    const int t = threadIdx.x, wave = t >> 6, lane = t & 63;
    const int quad = lane >> 4, l16 = lane & 15;
    const int tile = (wave < 4) ? pairtile : (15 - pairtile);
    const int wv = wave & 3;

    const short* Qb  = Qp + (size_t)bh * S_LEN * DK_H;
    const short* Kb  = Kp + (size_t)bh * S_LEN * DK_H;
    const short* Vtb = Vt + (size_t)bh * DK_H * S_LEN;   // [64][2048]

    const int q0 = tile * 128 + wv * 32;         // this wave's 32 q-rows
    const int ktimax = (q0 + 31) >> 6;

    short8 qf[2][2];
#pragma unroll
    for (int g = 0; g < 2; ++g)
#pragma unroll
        for (int ks = 0; ks < 2; ++ks)
            qf[g][ks] = *(const short8*)(Qb + (size_t)(q0 + g * 16 + l16) * DK_H + ks * 32 + quad * 8);

    // ones-column B-frag: C col 0 accumulates row sum
    short8 bl = {};
    if (l16 == 0) {
#pragma unroll
        for (int j = 0; j < 8; ++j) bl[j] = (short)0x3F80;   // bf16 1.0
    }

    floatx4 o[2][4] = {};
    floatx4 ol[2] = {};
    short* plw = &pl[wave][0];

    // K and V register double-buffers; preload kti=0
    short8 bk0[4][2], bk1[4][2], bv0[4][2], bv1[4][2];
#pragma unroll
    for (int nt = 0; nt < 4; ++nt)
#pragma unroll
        for (int ks = 0; ks < 2; ++ks) {
            bk0[nt][ks] = *(const short8*)(Kb + (size_t)(nt * 16 + l16) * DK_H + ks * 32 + quad * 8);
            bv0[nt][ks] = *(const short8*)(Vtb + (size_t)(nt * 16 + l16) * S_LEN + ks * 32 + quad * 8);
        }

    // one k-tile step: consumes bkc/bvc, prefetches kti+1 into bkn/bvn
    auto step = [&](int kti, short8 (&bkc)[4][2], short8 (&bkn)[4][2],
                    short8 (&bvc)[4][2], short8 (&bvn)[4][2]) {
        const int kbase = kti * 64;

        floatx4 sc[2][4] = {};
#pragma unroll
        for (int g = 0; g < 2; ++g)
#pragma unroll
            for (int nt = 0; nt < 4; ++nt)
#pragma unroll
                for (int ks = 0; ks < 2; ++ks)
                    sc[g][nt] = __builtin_amdgcn_mfma_f32_16x16x32_bf16(qf[g][ks], bkc[nt][ks], sc[g][nt], 0, 0, 0);

        if (kti < ktimax) {   // prefetch next K+V tiles (hidden by work below)
#pragma unroll
            for (int nt = 0; nt < 4; ++nt)
#pragma unroll
                for (int ks = 0; ks < 2; ++ks) {
                    bkn[nt][ks] = *(const short8*)(Kb + (size_t)(kbase + 64 + nt * 16 + l16) * DK_H + ks * 32 + quad * 8);
                    bvn[nt][ks] = *(const short8*)(Vtb + (size_t)(nt * 16 + l16) * S_LEN + kbase + 64 + ks * 32 + quad * 8);
                }
        }

        const bool diag = (kti == ktimax);

#pragma unroll
        for (int g = 0; g < 2; ++g) {
            const int qg = q0 + g * 16 + quad * 4;
            if (diag) {
#pragma unroll
                for (int nt = 0; nt < 4; ++nt) {
                    int key = kbase + nt * 16 + l16;
#pragma unroll
                    for (int r = 0; r < 4; ++r)
                        if (key > qg + r) sc[g][nt][r] = -1e30f;
                }
            }

            // p = 2^(s - SHIFT); C-layout -> LDS -> A-layout (wave-private)
#pragma unroll
            for (int nt = 0; nt < 4; ++nt)
#pragma unroll
                for (int r = 0; r < 4; ++r)
                    plw[(quad * 4 + r) * 72 + nt * 16 + l16] = f2b_t(exp2f(sc[g][nt][r] - SM_SHIFT));

            short8 ap0 = *(const short8*)(plw + l16 * 72 + quad * 8);
            short8 ap1 = *(const short8*)(plw + l16 * 72 + 32 + quad * 8);

#pragma unroll
            for (int nt = 0; nt < 4; ++nt) {
                o[g][nt] = __builtin_amdgcn_mfma_f32_16x16x32_bf16(ap0, bvc[nt][0], o[g][nt], 0, 0, 0);
                o[g][nt] = __builtin_amdgcn_mfma_f32_16x16x32_bf16(ap1, bvc[nt][1], o[g][nt], 0, 0, 0);
            }
            ol[g] = __builtin_amdgcn_mfma_f32_16x16x32_bf16(ap0, bl, ol[g], 0, 0, 0);
            ol[g] = __builtin_amdgcn_mfma_f32_16x16x32_bf16(ap1, bl, ol[g], 0, 0, 0);
        }
    };

    // manual x2 unroll: buffer selection is compile-time (no scratch)
    for (int kti = 0; kti <= ktimax; ) {
        step(kti, bk0, bk1, bv0, bv1);
        ++kti;
        if (kti <= ktimax) {
            step(kti, bk1, bk0, bv1, bv0);
            ++kti;
        }
    }

    // epilogue -> Xa [B,S,D] bf16. l for row quad*4+r lives in lane quad*16.
    const int b_ = bh >> 4, h = bh & 15;
#pragma unroll
    for (int g = 0; g < 2; ++g) {
#pragma unroll
        for (int r = 0; r < 4; ++r) {
            float lsum = __shfl(ol[g][r], (lane & 48));
            float rinv = 1.0f / lsum;
            int srow = q0 + g * 16 + quad * 4 + r;
#pragma unroll
            for (int nt = 0; nt < 4; ++nt) {
                int col = h * 64 + nt * 16 + l16;
                Xa[((size_t)b_ * S_LEN + srow) * D_MODEL + col] = f2b(o[g][nt][r] * rinv);
            }
        }
    }
}

// ---------------------------------------------------------------------------
// Output projection (m97 structure): out = Xa @ wo^T + bo (fp32)
// ---------------------------------------------------------------------------
__global__ __launch_bounds__(256)
void gemm_out_kernel(const short* __restrict__ A, const short* __restrict__ W,
                     const float* __restrict__ bias, float* __restrict__ out)
{
    __shared__ short sa[128 * 32];
    __shared__ short sb[128 * 32];

    const int nb = blockIdx.y * 128;
    const int m0 = blockIdx.x * 128;
    const int t = threadIdx.x, wave = t >> 6, lane = t & 63;
    const int quad = lane >> 4, l16 = lane & 15;
    const int wm = (wave & 1) * 64, wn = (wave >> 1) * 64;

    const int r0 = t >> 2, cs = t & 3;
    const int c0 = cs ^ ((r0 >> 1) & 3);
    const short* Ab0 = A + (size_t)(m0 + r0) * D_MODEL + c0 * 8;
    const short* Ab1 = Ab0 + (size_t)64 * D_MODEL;
    const short* Bb0 = W + (size_t)(nb + r0) * D_MODEL + c0 * 8;
    const short* Bb1 = Bb0 + (size_t)64 * D_MODEL;
    short* sa0 = sa + t * 8;  short* sa1 = sa + 2048 + t * 8;
    short* sb0 = sb + t * 8;  short* sb1 = sb + 2048 + t * 8;

    int a_off[4], b_off[4];
#pragma unroll
    for (int i = 0; i < 4; ++i) {
        int ar = wm + i * 16 + l16;
        a_off[i] = ar * 32 + ((quad ^ ((ar >> 1) & 3)) * 8);
        int br = wn + i * 16 + l16;
        b_off[i] = br * 32 + ((quad ^ ((br >> 1) & 3)) * 8);
    }

    floatx4 acc[4][4] = {};
    for (int k0 = 0; k0 < D_MODEL; k0 += 32) {
        __syncthreads();
        gload_lds16(Ab0 + k0, sa0);
        gload_lds16(Ab1 + k0, sa1);
        gload_lds16(Bb0 + k0, sb0);
        gload_lds16(Bb1 + k0, sb1);
        __syncthreads();
        short8 af[4], bf[4];
#pragma unroll
        for (int i = 0; i < 4; ++i) af[i] = *(const short8*)(sa + a_off[i]);
#pragma unroll
        for (int i = 0; i < 4; ++i) bf[i] = *(const short8*)(sb + b_off[i]);
#pragma unroll
        for (int mt = 0; mt < 4; ++mt)
#pragma unroll
            for (int nt = 0; nt < 4; ++nt)
                acc[mt][nt] = __builtin_amdgcn_mfma_f32_16x16x32_bf16(af[mt], bf[nt], acc[mt][nt], 0, 0, 0);
    }

#pragma unroll
    for (int nt = 0; nt < 4; ++nt) {
        int ncol = nb + wn + nt * 16 + l16;
        float bv_ = bias[ncol];
#pragma unroll
        for (int mt = 0; mt < 4; ++mt) {
            int mrow0 = m0 + wm + mt * 16 + quad * 4;
#pragma unroll
            for (int r = 0; r < 4; ++r)
                out[(size_t)(mrow0 + r) * D_MODEL + ncol] = acc[mt][nt][r] + bv_;
        }
    }
}

// ---------------------------------------------------------------------------
extern "C" void kernel_launch(void* const* d_in, const int* in_sizes, int n_in,
                              void* d_out, int out_size, void* d_ws, size_t ws_size,
                              hipStream_t stream)
{
    (void)in_sizes; (void)n_in; (void)out_size; (void)ws_size;
    const float* q  = (const float*)d_in[0];
    const float* k  = (const float*)d_in[1];
    const float* v  = (const float*)d_in[2];
    // d_in[3] = causal mask: analytic, unused
    const float* wq = (const float*)d_in[4];
    const float* bq = (const float*)d_in[5];
    const float* wk = (const float*)d_in[6];
    const float* bk = (const float*)d_in[7];
    const float* wv = (const float*)d_in[8];
    const float* bv = (const float*)d_in[9];
    const float* wo = (const float*)d_in[10];
    const float* bo = (const float*)d_in[11];
    float* out = (float*)d_out;

    const size_t XE = (size_t)M_ROWS * D_MODEL;
    const size_t WE = (size_t)D_MODEL * D_MODEL;
    short* ws_  = (short*)d_ws;
    short* xq_b = ws_;             // XE (reused as Xa after QKV GEMM)
    short* xk_b = xq_b + XE;
    short* xv_b = xk_b + XE;
    short* wq_b = xv_b + XE;
    short* wk_b = wq_b + WE;
    short* wv_b = wk_b + WE;
    short* wo_b = wv_b + WE;
    short* Qp   = wo_b + WE;       // [B,H,S,DK]
    short* Kp   = Qp + XE;
    short* Vt   = Kp + XE;         // [B,H,DK,S]
    short* Xa   = xq_b;

    dim3 blk(256);
    cvt_all_kernel<<<dim3(1024, 7), blk, 0, stream>>>(
        q, k, v, wq, wk, wv, wo, xq_b, xk_b, xv_b, wq_b, wk_b, wv_b, wo_b);

    gemm_qkv_kernel<<<dim3(M_ROWS / 128, 24), blk, 0, stream>>>(
        xq_b, xk_b, xv_b, wq_b, wk_b, wv_b, bq, bk, bv, Qp, Kp, Vt);

    attn_kernel<<<dim3(8, B_SZ * H_NUM), dim3(512), 0, stream>>>(Qp, Kp, Vt, Xa);

    gemm_out_kernel<<<dim3(M_ROWS / 128, D_MODEL / 128), blk, 0, stream>>>(Xa, wo_b, bo, out);
}

// Round 9
// 261.220 us; speedup vs baseline: 1.0432x; 1.0432x over previous
//
#include <hip/hip_runtime.h>

#define B_SZ    2
#define S_LEN   2048
#define D_MODEL 1024
#define H_NUM   16
#define DK_H    64
#define M_ROWS  (B_SZ * S_LEN)   // 4096

typedef __attribute__((ext_vector_type(8))) short  short8;
typedef __attribute__((ext_vector_type(4))) short  short4v;
typedef __attribute__((ext_vector_type(4))) float  floatx4;

// fp32 -> bf16 round-to-nearest-even (finite inputs only)
__device__ __forceinline__ short f2b(float f) {
    union { float f; unsigned u; } x; x.f = f;
    unsigned u = x.u + 0x7fffu + ((x.u >> 16) & 1u);
    return (short)(u >> 16);
}
// truncating fp32 -> bf16 (for P in [0, 2^-5]: bias cancels in O/l ratio)
__device__ __forceinline__ short f2b_t(float f) {
    union { float f; unsigned u; } x; x.f = f;
    return (short)(x.u >> 16);
}

typedef __attribute__((address_space(1))) const unsigned int gu32;
typedef __attribute__((address_space(3))) unsigned int       lu32;
__device__ __forceinline__ void gload_lds16(const short* g, short* l) {
    __builtin_amdgcn_global_load_lds((gu32*)g, (lu32*)l, 16, 0, 0);
}

// log2(e)/sqrt(DK): folded into Q so softmax runs in exp2 domain
#define QSCALE 0.18033688011112042f
// fixed softmax shift (exp2-domain scores ~N(0,1.44); 12 >> any row max)
#define SM_SHIFT 12.0f

// ---------------------------------------------------------------------------
// fp32 -> bf16 convert, all 7 tensors in one launch.
// grid (1024, 7), 256 thr. y<3: x-tensors (4 passes); y>=3: weights (1 pass).
// ---------------------------------------------------------------------------
__global__ void cvt_all_kernel(const float* __restrict__ xq, const float* __restrict__ xk,
                               const float* __restrict__ xv, const float* __restrict__ wq,
                               const float* __restrict__ wk, const float* __restrict__ wv,
                               const float* __restrict__ wo,
                               short* __restrict__ oxq, short* __restrict__ oxk,
                               short* __restrict__ oxv, short* __restrict__ owq,
                               short* __restrict__ owk, short* __restrict__ owv,
                               short* __restrict__ owo)
{
    const int y = blockIdx.y;
    const float* in;
    short* out;
    switch (y) {
        case 0: in = xq; out = oxq; break;
        case 1: in = xk; out = oxk; break;
        case 2: in = xv; out = oxv; break;
        case 3: in = wq; out = owq; break;
        case 4: in = wk; out = owk; break;
        case 5: in = wv; out = owv; break;
        default: in = wo; out = owo; break;
    }
    const int npass = (y < 3) ? 4 : 1;
    int base = blockIdx.x * 1024 + threadIdx.x * 4;
    for (int p = 0; p < npass; ++p) {
        int i = base + p * 1048576;
        float4 v = *(const float4*)(in + i);
        short4v r;
        r[0] = f2b(v.x); r[1] = f2b(v.y); r[2] = f2b(v.z); r[3] = f2b(v.w);
        *(short4v*)(out + i) = r;
    }
}

// ---------------------------------------------------------------------------
// Fused QKV projection (m97 structure). Q scaled by log2e/8. Q,K out
// [B,H,S,DK]; V out transposed [B,H,DK,S].
// ---------------------------------------------------------------------------
__global__ __launch_bounds__(256)
void gemm_qkv_kernel(const short* __restrict__ xq, const short* __restrict__ xk,
                     const short* __restrict__ xv,
                     const short* __restrict__ wq, const short* __restrict__ wk,
                     const short* __restrict__ wv,
                     const float* __restrict__ bq, const float* __restrict__ bk,
                     const float* __restrict__ bv,
                     short* __restrict__ Qp, short* __restrict__ Kp, short* __restrict__ Vt)
{
    __shared__ short sa[128 * 32];
    __shared__ short sb[128 * 32];

    const int which = blockIdx.y >> 3;
    const short* A    = (which == 0) ? xq : (which == 1) ? xk : xv;
    const short* W    = (which == 0) ? wq : (which == 1) ? wk : wv;
    const float* bias = (which == 0) ? bq : (which == 1) ? bk : bv;
    const float scale = (which == 0) ? QSCALE : 1.0f;

    const int nb = (blockIdx.y & 7) * 128;
    const int m0 = blockIdx.x * 128;
    const int t = threadIdx.x, wave = t >> 6, lane = t & 63;
    const int quad = lane >> 4, l16 = lane & 15;
    const int wm = (wave & 1) * 64, wn = (wave >> 1) * 64;

    const int r0 = t >> 2, cs = t & 3;
    const int c0 = cs ^ ((r0 >> 1) & 3);
    const short* Ab0 = A + (size_t)(m0 + r0) * D_MODEL + c0 * 8;
    const short* Ab1 = Ab0 + (size_t)64 * D_MODEL;
    const short* Bb0 = W + (size_t)(nb + r0) * D_MODEL + c0 * 8;
    const short* Bb1 = Bb0 + (size_t)64 * D_MODEL;
    short* sa0 = sa + t * 8;  short* sa1 = sa + 2048 + t * 8;
    short* sb0 = sb + t * 8;  short* sb1 = sb + 2048 + t * 8;

    int a_off[4], b_off[4];
#pragma unroll
    for (int i = 0; i < 4; ++i) {
        int ar = wm + i * 16 + l16;
        a_off[i] = ar * 32 + ((quad ^ ((ar >> 1) & 3)) * 8);
        int br = wn + i * 16 + l16;
        b_off[i] = br * 32 + ((quad ^ ((br >> 1) & 3)) * 8);
    }

    floatx4 acc[4][4] = {};
    for (int k0 = 0; k0 < D_MODEL; k0 += 32) {
        __syncthreads();
        gload_lds16(Ab0 + k0, sa0);
        gload_lds16(Ab1 + k0, sa1);
        gload_lds16(Bb0 + k0, sb0);
        gload_lds16(Bb1 + k0, sb1);
        __syncthreads();
        short8 af[4], bf[4];
#pragma unroll
        for (int i = 0; i < 4; ++i) af[i] = *(const short8*)(sa + a_off[i]);
#pragma unroll
        for (int i = 0; i < 4; ++i) bf[i] = *(const short8*)(sb + b_off[i]);
#pragma unroll
        for (int mt = 0; mt < 4; ++mt)
#pragma unroll
            for (int nt = 0; nt < 4; ++nt)
                acc[mt][nt] = __builtin_amdgcn_mfma_f32_16x16x32_bf16(af[mt], bf[nt], acc[mt][nt], 0, 0, 0);
    }

#pragma unroll
    for (int nt = 0; nt < 4; ++nt) {
        int ncol = nb + wn + nt * 16 + l16;
        int h = ncol >> 6, dk = ncol & 63;
        float bv_ = bias[ncol];
#pragma unroll
        for (int mt = 0; mt < 4; ++mt) {
            int mrow0 = m0 + wm + mt * 16 + quad * 4;
            int bb = mrow0 >> 11, s0 = mrow0 & (S_LEN - 1);
            if (which < 2) {
                short* Out = (which == 0) ? Qp : Kp;
#pragma unroll
                for (int r = 0; r < 4; ++r) {
                    float v = (acc[mt][nt][r] + bv_) * scale;
                    Out[(((size_t)bb * H_NUM + h) * S_LEN + (s0 + r)) * DK_H + dk] = f2b(v);
                }
            } else {
                short4v pk;
#pragma unroll
                for (int r = 0; r < 4; ++r) pk[r] = f2b(acc[mt][nt][r] + bv_);
                *(short4v*)(&Vt[(((size_t)bb * H_NUM + h) * DK_H + dk) * S_LEN + s0]) = pk;
            }
        }
    }
}

// ---------------------------------------------------------------------------
// Balanced flash attention, XCD-local KV (R8 swizzle: bh = c&31 -> all 8
// blocks of a bh on XCD bh%8, 4 bh x ~0.75MB per XCD L2). Block = 8 waves:
// waves 0-3 tile p, waves 4-7 tile 15-p (per-SIMD work uniform chip-wide).
// Wave = 32 q-rows. K double-buffered in registers (static selection via
// manual x2 unroll -- dynamic indexing spills to scratch, R6 lesson).
// V loaded at ITERATION TOP, consumed after softmax (~400cyc slack); NO V
// double-buffer (R8 lesson: +64 VGPR live state -> 128 VGPR + scratch).
// Fixed-shift exp2 softmax; row-sum via ones-column MFMA. No barriers.
// ---------------------------------------------------------------------------
__global__ __launch_bounds__(512, 2)
void attn_kernel(const short* __restrict__ Qp, const short* __restrict__ Kp,
                 const short* __restrict__ Vt, short* __restrict__ Xa)
{
    __shared__ short pl[8][16 * 72];   // per-wave P round-trip

    const int c = (int)(blockIdx.x + 8 * blockIdx.y);
    const int bh = c & 31;                       // XCD = bh % 8
    const int pairtile = c >> 5;                 // [0,8)
    const int t = threadIdx.x, wave = t >> 6, lane = t & 63;
    const int quad = lane >> 4, l16 = lane & 15;
    const int tile = (wave < 4) ? pairtile : (15 - pairtile);
    const int wv = wave & 3;

    const short* Qb  = Qp + (size_t)bh * S_LEN * DK_H;
    const short* Kb  = Kp + (size_t)bh * S_LEN * DK_H;
    const short* Vtb = Vt + (size_t)bh * DK_H * S_LEN;   // [64][2048]

    const int q0 = tile * 128 + wv * 32;         // this wave's 32 q-rows
    const int ktimax = (q0 + 31) >> 6;

    short8 qf[2][2];
#pragma unroll
    for (int g = 0; g < 2; ++g)
#pragma unroll
        for (int ks = 0; ks < 2; ++ks)
            qf[g][ks] = *(const short8*)(Qb + (size_t)(q0 + g * 16 + l16) * DK_H + ks * 32 + quad * 8);

    // ones-column B-frag: C col 0 accumulates row sum
    short8 bl = {};
    if (l16 == 0) {
#pragma unroll
        for (int j = 0; j < 8; ++j) bl[j] = (short)0x3F80;   // bf16 1.0
    }

    floatx4 o[2][4] = {};
    floatx4 ol[2] = {};
    short* plw = &pl[wave][0];

    // K register double-buffer; preload kti=0
    short8 bk0[4][2], bk1[4][2];
#pragma unroll
    for (int nt = 0; nt < 4; ++nt)
#pragma unroll
        for (int ks = 0; ks < 2; ++ks)
            bk0[nt][ks] = *(const short8*)(Kb + (size_t)(nt * 16 + l16) * DK_H + ks * 32 + quad * 8);

    // one k-tile step: consumes bkc, prefetches kti+1's K into bkn
    auto step = [&](int kti, short8 (&bkc)[4][2], short8 (&bkn)[4][2]) {
        const int kbase = kti * 64;

        // V frags for the CURRENT tile, issued first: consumed only after
        // softmax (~400cyc slack covers the L2 hit)
        short8 bv[4][2];
#pragma unroll
        for (int nt = 0; nt < 4; ++nt)
#pragma unroll
            for (int ks = 0; ks < 2; ++ks)
                bv[nt][ks] = *(const short8*)(Vtb + (size_t)(nt * 16 + l16) * S_LEN + kbase + ks * 32 + quad * 8);

        floatx4 sc[2][4] = {};
#pragma unroll
        for (int g = 0; g < 2; ++g)
#pragma unroll
            for (int nt = 0; nt < 4; ++nt)
#pragma unroll
                for (int ks = 0; ks < 2; ++ks)
                    sc[g][nt] = __builtin_amdgcn_mfma_f32_16x16x32_bf16(qf[g][ks], bkc[nt][ks], sc[g][nt], 0, 0, 0);

        if (kti < ktimax) {   // prefetch next K tile (hidden by softmax+PV)
#pragma unroll
            for (int nt = 0; nt < 4; ++nt)
#pragma unroll
                for (int ks = 0; ks < 2; ++ks)
                    bkn[nt][ks] = *(const short8*)(Kb + (size_t)(kbase + 64 + nt * 16 + l16) * DK_H + ks * 32 + quad * 8);
        }

        const bool diag = (kti == ktimax);

#pragma unroll
        for (int g = 0; g < 2; ++g) {
            const int qg = q0 + g * 16 + quad * 4;
            if (diag) {
#pragma unroll
                for (int nt = 0; nt < 4; ++nt) {
                    int key = kbase + nt * 16 + l16;
#pragma unroll
                    for (int r = 0; r < 4; ++r)
                        if (key > qg + r) sc[g][nt][r] = -1e30f;
                }
            }

            // p = 2^(s - SHIFT); C-layout -> LDS -> A-layout (wave-private)
#pragma unroll
            for (int nt = 0; nt < 4; ++nt)
#pragma unroll
                for (int r = 0; r < 4; ++r)
                    plw[(quad * 4 + r) * 72 + nt * 16 + l16] = f2b_t(exp2f(sc[g][nt][r] - SM_SHIFT));

            short8 ap0 = *(const short8*)(plw + l16 * 72 + quad * 8);
            short8 ap1 = *(const short8*)(plw + l16 * 72 + 32 + quad * 8);

#pragma unroll
            for (int nt = 0; nt < 4; ++nt) {
                o[g][nt] = __builtin_amdgcn_mfma_f32_16x16x32_bf16(ap0, bv[nt][0], o[g][nt], 0, 0, 0);
                o[g][nt] = __builtin_amdgcn_mfma_f32_16x16x32_bf16(ap1, bv[nt][1], o[g][nt], 0, 0, 0);
            }
            ol[g] = __builtin_amdgcn_mfma_f32_16x16x32_bf16(ap0, bl, ol[g], 0, 0, 0);
            ol[g] = __builtin_amdgcn_mfma_f32_16x16x32_bf16(ap1, bl, ol[g], 0, 0, 0);
        }
    };

    // manual x2 unroll: K-buffer selection is compile-time (no scratch)
    for (int kti = 0; kti <= ktimax; ) {
        step(kti, bk0, bk1);
        ++kti;
        if (kti <= ktimax) {
            step(kti, bk1, bk0);
            ++kti;
        }
    }

    // epilogue -> Xa [B,S,D] bf16. l for row quad*4+r lives in lane quad*16.
    const int b_ = bh >> 4, h = bh & 15;
#pragma unroll
    for (int g = 0; g < 2; ++g) {
#pragma unroll
        for (int r = 0; r < 4; ++r) {
            float lsum = __shfl(ol[g][r], (lane & 48));
            float rinv = 1.0f / lsum;
            int srow = q0 + g * 16 + quad * 4 + r;
#pragma unroll
            for (int nt = 0; nt < 4; ++nt) {
                int col = h * 64 + nt * 16 + l16;
                Xa[((size_t)b_ * S_LEN + srow) * D_MODEL + col] = f2b(o[g][nt][r] * rinv);
            }
        }
    }
}

// ---------------------------------------------------------------------------
// Output projection (m97 structure): out = Xa @ wo^T + bo (fp32)
// ---------------------------------------------------------------------------
__global__ __launch_bounds__(256)
void gemm_out_kernel(const short* __restrict__ A, const short* __restrict__ W,
                     const float* __restrict__ bias, float* __restrict__ out)
{
    __shared__ short sa[128 * 32];
    __shared__ short sb[128 * 32];

    const int nb = blockIdx.y * 128;
    const int m0 = blockIdx.x * 128;
    const int t = threadIdx.x, wave = t >> 6, lane = t & 63;
    const int quad = lane >> 4, l16 = lane & 15;
    const int wm = (wave & 1) * 64, wn = (wave >> 1) * 64;

    const int r0 = t >> 2, cs = t & 3;
    const int c0 = cs ^ ((r0 >> 1) & 3);
    const short* Ab0 = A + (size_t)(m0 + r0) * D_MODEL + c0 * 8;
    const short* Ab1 = Ab0 + (size_t)64 * D_MODEL;
    const short* Bb0 = W + (size_t)(nb + r0) * D_MODEL + c0 * 8;
    const short* Bb1 = Bb0 + (size_t)64 * D_MODEL;
    short* sa0 = sa + t * 8;  short* sa1 = sa + 2048 + t * 8;
    short* sb0 = sb + t * 8;  short* sb1 = sb + 2048 + t * 8;

    int a_off[4], b_off[4];
#pragma unroll
    for (int i = 0; i < 4; ++i) {
        int ar = wm + i * 16 + l16;
        a_off[i] = ar * 32 + ((quad ^ ((ar >> 1) & 3)) * 8);
        int br = wn + i * 16 + l16;
        b_off[i] = br * 32 + ((quad ^ ((br >> 1) & 3)) * 8);
    }

    floatx4 acc[4][4] = {};
    for (int k0 = 0; k0 < D_MODEL; k0 += 32) {
        __syncthreads();
        gload_lds16(Ab0 + k0, sa0);
        gload_lds16(Ab1 + k0, sa1);
        gload_lds16(Bb0 + k0, sb0);
        gload_lds16(Bb1 + k0, sb1);
        __syncthreads();
        short8 af[4], bf[4];
#pragma unroll
    for (int i = 0; i < 4; ++i) af[i] = *(const short8*)(sa + a_off[i]);
#pragma unroll
        for (int i = 0; i < 4; ++i) bf[i] = *(const short8*)(sb + b_off[i]);
#pragma unroll
        for (int mt = 0; mt < 4; ++mt)
#pragma unroll
            for (int nt = 0; nt < 4; ++nt)
                acc[mt][nt] = __builtin_amdgcn_mfma_f32_16x16x32_bf16(af[mt], bf[nt], acc[mt][nt], 0, 0, 0);
    }

#pragma unroll
    for (int nt = 0; nt < 4; ++nt) {
        int ncol = nb + wn + nt * 16 + l16;
        float bv_ = bias[ncol];
#pragma unroll
        for (int mt = 0; mt < 4; ++mt) {
            int mrow0 = m0 + wm + mt * 16 + quad * 4;
#pragma unroll
            for (int r = 0; r < 4; ++r)
                out[(size_t)(mrow0 + r) * D_MODEL + ncol] = acc[mt][nt][r] + bv_;
        }
    }
}

// ---------------------------------------------------------------------------
extern "C" void kernel_launch(void* const* d_in, const int* in_sizes, int n_in,
                              void* d_out, int out_size, void* d_ws, size_t ws_size,
                              hipStream_t stream)
{
    (void)in_sizes; (void)n_in; (void)out_size; (void)ws_size;
    const float* q  = (const float*)d_in[0];
    const float* k  = (const float*)d_in[1];
    const float* v  = (const float*)d_in[2];
    // d_in[3] = causal mask: analytic, unused
    const float* wq = (const float*)d_in[4];
    const float* bq = (const float*)d_in[5];
    const float* wk = (const float*)d_in[6];
    const float* bk = (const float*)d_in[7];
    const float* wv = (const float*)d_in[8];
    const float* bv = (const float*)d_in[9];
    const float* wo = (const float*)d_in[10];
    const float* bo = (const float*)d_in[11];
    float* out = (float*)d_out;

    const size_t XE = (size_t)M_ROWS * D_MODEL;
    const size_t WE = (size_t)D_MODEL * D_MODEL;
    short* ws_  = (short*)d_ws;
    short* xq_b = ws_;             // XE (reused as Xa after QKV GEMM)
    short* xk_b = xq_b + XE;
    short* xv_b = xk_b + XE;
    short* wq_b = xv_b + XE;
    short* wk_b = wq_b + WE;
    short* wv_b = wk_b + WE;
    short* wo_b = wv_b + WE;
    short* Qp   = wo_b + WE;       // [B,H,S,DK]
    short* Kp   = Qp + XE;
    short* Vt   = Kp + XE;         // [B,H,DK,S]
    short* Xa   = xq_b;

    dim3 blk(256);
    cvt_all_kernel<<<dim3(1024, 7), blk, 0, stream>>>(
        q, k, v, wq, wk, wv, wo, xq_b, xk_b, xv_b, wq_b, wk_b, wv_b, wo_b);

    gemm_qkv_kernel<<<dim3(M_ROWS / 128, 24), blk, 0, stream>>>(
        xq_b, xk_b, xv_b, wq_b, wk_b, wv_b, bq, bk, bv, Qp, Kp, Vt);

    attn_kernel<<<dim3(8, B_SZ * H_NUM), dim3(512), 0, stream>>>(Qp, Kp, Vt, Xa);

    gemm_out_kernel<<<dim3(M_ROWS / 128, D_MODEL / 128), blk, 0, stream>>>(Xa, wo_b, bo, out);
}